// Round 11
// baseline (196.923 us; speedup 1.0000x reference)
//
#include <hip/hip_runtime.h>
#include <hip/hip_bf16.h>
#include <stdint.h>

#define SEQ 4096
#define DM  1024

typedef __attribute__((ext_vector_type(8))) short bf16x8;
typedef __attribute__((ext_vector_type(4))) float f32x4;

template <int V> struct Int { static constexpr int v = V; };

__device__ __forceinline__ short f2bf(float f) {
  union { float f; unsigned int i; } x; x.f = f;
  unsigned int r = x.i + 0x7FFFu + ((x.i >> 16) & 1u);
  return (short)(r >> 16);
}
__device__ __forceinline__ float bf2f(short s) {
  union { unsigned int i; float f; } u;
  u.i = ((unsigned int)(unsigned short)s) << 16;
  return u.f;
}

__device__ __forceinline__ void gload16(const short* g, short* l) {
  __builtin_amdgcn_global_load_lds(
      (const __attribute__((address_space(1))) unsigned int*)g,
      (__attribute__((address_space(3))) unsigned int*)l, 16, 0, 0);
}

__device__ __forceinline__ float wave_max(float v) {
#pragma unroll
  for (int o = 32; o; o >>= 1) v = fmaxf(v, __shfl_xor(v, o));
  return v;
}
__device__ __forceinline__ float wave_sum(float v) {
#pragma unroll
  for (int o = 32; o; o >>= 1) v += __shfl_xor(v, o);
  return v;
}

#define BARRIER() do { asm volatile("" ::: "memory"); \
  __builtin_amdgcn_s_barrier(); asm volatile("" ::: "memory"); } while (0)
#define MF(a, b, c) __builtin_amdgcn_mfma_f32_16x16x32_bf16(a, b, c, 0, 0, 0)

// ---------------------------------------------------------------------------
// 256x256-tile bf16 GEMM, 16x16x32 MFMA, DEEP-PREFETCH buffering:
// A-tiles triple-buffered (3 x 32 KiB), B-tiles double-buffered (2 x 32 KiB)
// = 160 KiB LDS exactly. Uniform 4-phase group per K-tile t
// (A-buf = t%3, B-buf = t&1):
//   P1: ldbf all 8 B-frags + ldaf c=0 + stage A(t+2) both halves
//       -> MFMA c0 -> BARRIER (arrival proves every wave's ldbf completed,
//          so P2's stB overwrite of this B-buf is race-free)
//   P2: ldaf c=1 + stage B(t+2) half 0 -> MFMA c1
//   P3: ldaf c=2 + stage B(t+2) half 1 -> MFMA c2
//   P4: ldaf c=3 -> MFMA c3
//   boundary (skip on last tile): vmcnt(8 if staged else 0) + BARRIER
// Ledger: 8 loads issued/group; 16 outstanding at the boundary; vmcnt(8)
// drains exactly tile t+1's 8 loads, which are 5-7 phases old (vs 3 in the
// 2-buffer scheme) -> load latency hidden, boundary stall removed.
// Stage-hazard audit: stA targets A-buf (t+2)%3 = (t-1)%3, last read P4 of
// group t-1, protected by that group's boundary barrier. stB targets B-buf
// t&1, read only at P1 of this group, protected by the P1-end barrier.
// LDS swizzle (3-bit): byte ^= ((byte>>7)&7)<<4; involution pre-applied to
// the gload source. 0 bank conflicts (verified rounds 5-10).
// EPI: 0 plain bf16; 1 +bias; 2 *scale; 3 QKV (bias, v-cols -> transposed Cv).
// ---------------------------------------------------------------------------
template <int EPI>
__global__ __launch_bounds__(512, 2) void gemm8(
    const short* __restrict__ A, const short* __restrict__ B,
    short* __restrict__ C, short* __restrict__ Cv,
    const float* __restrict__ bias, int Ksplit, int lda, int ldb, int ldc,
    int ldv, float scale, int ntm, int ntn, long csplit, int pc) {
  __shared__ short ldsA[3][2][8192];  // [buf][half][128 rows x 64 k]
  __shared__ short ldsB[2][2][8192];
  const int tid = threadIdx.x;
  const int lane = tid & 63;
  const int wid = tid >> 6;   // 0..7
  const int wr = wid >> 2;    // 0,1  -> A half / output row half
  const int wc = wid & 3;     // 0..3 -> 64-col group
  const int bid = blockIdx.x, nwg = gridDim.x;
  const int chunk = nwg >> 3;
  const int wl = (bid & 7) * chunk + (bid >> 3);  // contiguous per XCD
  const int tpg = ntm * ntn;
  const int split = wl / tpg;
  const int r0 = wl - split * tpg;
  const int q = r0 / chunk, i0 = r0 % chunk;
  const int npatch = ntn / pc;
  const int m0 = ((q / npatch) * (chunk / pc) + i0 / pc) * 256;
  const int n0 = ((q % npatch) * pc + i0 % pc) * 256;
  const short* Ab = A + (long)split * Ksplit;
  const short* Bb = B + (long)split * Ksplit;
  short* Co = C + (long)split * csplit;

  // staging: thread t fills half-tile bytes [t*16, t*16+16) linearly; source
  // address pre-swizzled with the involution swz(b) = b ^ (((b>>7)&7)<<4).
  const int o0 = tid * 16;
  const int oo = o0 ^ (((o0 >> 7) & 7) << 4);
  const int sr0 = oo >> 7;           // source row 0..63
  const int sc0 = (oo & 127) >> 1;   // source col in shorts (8-mult)

  auto stA = [&](int buf, int h, int kt) {
    const short* g = Ab + (long)(m0 + h * 128 + sr0) * lda + kt * 64 + sc0;
    short* l = &ldsA[buf][h][0] + wid * 512;
    gload16(g, l);
    gload16(g + (long)64 * lda, l + 4096);
  };
  auto stB = [&](int buf, int h, int kt) {
    const short* g = Bb + (long)(n0 + h * 128 + sr0) * ldb + kt * 64 + sc0;
    short* l = &ldsB[buf][h][0] + wid * 512;
    gload16(g, l);
    gload16(g + (long)64 * ldb, l + 4096);
  };

  const int ll = lane & 15, lh = lane >> 4;
  // fragment reads: short-offset XOR (r&7)<<3 == byte XOR (r&7)<<4
  auto ldaf = [&](int buf, int c, int mm, int kk) {
    const int r = c * 32 + mm * 16 + ll;
    const int off = (r * 64 + kk * 32 + lh * 8) ^ ((r & 7) << 3);
    return *(const bf16x8*)(&ldsA[buf][wr][0] + off);
  };
  auto ldbf = [&](int buf, int n, int kk) {
    const int r = (wc & 1) * 64 + n * 16 + ll;
    const int off = (r * 64 + kk * 32 + lh * 8) ^ ((r & 7) << 3);
    return *(const bf16x8*)(&ldsB[buf][wc >> 1][0] + off);
  };

  f32x4 acc[8][4];
#pragma unroll
  for (int i = 0; i < 8; i++)
#pragma unroll
    for (int j = 0; j < 4; j++) acc[i][j] = (f32x4){0.f, 0.f, 0.f, 0.f};
  bf16x8 Bf[4][2];

  const int NT = Ksplit >> 6;  // >= 4 at all call sites
  // prologue: tiles 0 and 1 fully staged (16 loads); vmcnt(8) drains tile 0.
  stA(0, 0, 0); stA(0, 1, 0); stB(0, 0, 0); stB(0, 1, 0);
  stA(1, 0, 1); stA(1, 1, 1); stB(1, 0, 1); stB(1, 1, 1);
  asm volatile("s_waitcnt vmcnt(8)" ::: "memory");
  BARRIER();

  // phase: [A-frag reads] [stage hook] [16 MFMA] [barrier?]
  auto phase = [&](auto CC, int abuf, auto&& stg, bool bar) {
    constexpr int c = decltype(CC)::v;
    bf16x8 a00 = ldaf(abuf, c, 0, 0), a01 = ldaf(abuf, c, 0, 1);
    bf16x8 a10 = ldaf(abuf, c, 1, 0), a11 = ldaf(abuf, c, 1, 1);
    stg();
    __builtin_amdgcn_s_setprio(1);
#pragma unroll
    for (int n = 0; n < 4; n++) {
      acc[2 * c][n] = MF(a00, Bf[n][0], acc[2 * c][n]);
      acc[2 * c][n] = MF(a01, Bf[n][1], acc[2 * c][n]);
      acc[2 * c + 1][n] = MF(a10, Bf[n][0], acc[2 * c + 1][n]);
      acc[2 * c + 1][n] = MF(a11, Bf[n][1], acc[2 * c + 1][n]);
    }
    __builtin_amdgcn_s_setprio(0);
    if (bar) BARRIER();
  };

  int a3 = 0;  // t % 3
  for (int t = 0; t < NT; ++t) {
    const int b2 = t & 1;
    int an = a3 - 1; if (an < 0) an = 2;  // (t+2) % 3
    const bool st = (t + 2 < NT);
    const bool last = (t == NT - 1);
    // P1: all B-frags for tile t (register-held through P4)
#pragma unroll
    for (int n = 0; n < 4; n++) {
      Bf[n][0] = ldbf(b2, n, 0);
      Bf[n][1] = ldbf(b2, n, 1);
    }
    phase(Int<0>{}, a3,
          [&] { if (st) { stA(an, 0, t + 2); stA(an, 1, t + 2); } }, true);
    phase(Int<1>{}, a3, [&] { if (st) stB(b2, 0, t + 2); }, false);
    phase(Int<2>{}, a3, [&] { if (st) stB(b2, 1, t + 2); }, false);
    phase(Int<3>{}, a3, [&] {}, false);
    if (!last) {
      if (st) { asm volatile("s_waitcnt vmcnt(8)" ::: "memory"); }
      else    { asm volatile("s_waitcnt vmcnt(0)" ::: "memory"); }
      BARRIER();
    }
    a3 = (a3 + 1 == 3) ? 0 : a3 + 1;
  }

  // epilogue: wave writes 128x64 at (m0 + wr*128, n0 + wc*64)
  const int rb = m0 + wr * 128 + lh * 4;
  const int cb0 = n0 + wc * 64 + ll;
  if (EPI == 3 && n0 >= 2048) {
    // v-block: bias + packed transposed write to vT[col-2048][row]
#pragma unroll
    for (int mi = 0; mi < 8; mi++) {
#pragma unroll
      for (int n = 0; n < 4; n++) {
        const int col = cb0 + n * 16;
        const float bv = bias[col];
        short4 pk;
        pk.x = f2bf(acc[mi][n][0] + bv);
        pk.y = f2bf(acc[mi][n][1] + bv);
        pk.z = f2bf(acc[mi][n][2] + bv);
        pk.w = f2bf(acc[mi][n][3] + bv);
        *(short4*)(Cv + (long)(col - 2048) * ldv + rb + mi * 16) = pk;
      }
    }
    return;
  }
#pragma unroll
  for (int mi = 0; mi < 8; mi++) {
#pragma unroll
    for (int n = 0; n < 4; n++) {
      const int col = cb0 + n * 16;
      float bv = 0.f;
      if (EPI == 1 || EPI == 3) bv = bias[col];
#pragma unroll
      for (int r = 0; r < 4; r++) {
        const int row = rb + mi * 16 + r;
        const long off = (long)row * ldc + col;
        float v = acc[mi][n][r];
        if (EPI == 1 || EPI == 3) v += bv;
        if (EPI == 2) v *= scale;
        Co[off] = f2bf(v);
      }
    }
  }
}

// ---------------------------------------------------------------------------

__global__ __launch_bounds__(256) void cvt_f32_to_bf16(
    const float* __restrict__ in, short* __restrict__ out, int n4) {
  int i = blockIdx.x * 256 + threadIdx.x;
  if (i < n4) {
    float4 f = ((const float4*)in)[i];
    short4 o;
    o.x = f2bf(f.x); o.y = f2bf(f.y); o.z = f2bf(f.z); o.w = f2bf(f.w);
    ((short4*)out)[i] = o;
  }
}

// four 1024x1024 fp32 -> bf16 transposes in one launch (z picks the matrix)
__global__ void transpose_w4(const float* __restrict__ s0,
                             const float* __restrict__ s1,
                             const float* __restrict__ s2,
                             const float* __restrict__ s3,
                             short* __restrict__ d0, short* __restrict__ d1,
                             short* __restrict__ d2, short* __restrict__ d3) {
  const int z = blockIdx.z;
  const float* in = z == 0 ? s0 : z == 1 ? s1 : z == 2 ? s2 : s3;
  short* out = z == 0 ? d0 : z == 1 ? d1 : z == 2 ? d2 : d3;
  __shared__ float tile[32][33];
  const int bx = blockIdx.x * 32;
  const int by = blockIdx.y * 32;
  const int tx = threadIdx.x, ty = threadIdx.y;
#pragma unroll
  for (int i = 0; i < 32; i += 8)
    tile[ty + i][tx] = in[(long)(by + ty + i) * 1024 + bx + tx];
  __syncthreads();
#pragma unroll
  for (int i = 0; i < 32; i += 8)
    out[(long)(bx + ty + i) * 1024 + by + tx] = f2bf(tile[tx][ty + i]);
}

// bqkv = [bq | bk | bv]
__global__ __launch_bounds__(256) void concat_bias(
    const float* __restrict__ bq, const float* __restrict__ bk,
    const float* __restrict__ bv, float* __restrict__ o) {
  int i = blockIdx.x * 256 + threadIdx.x;  // 0..3071
  float v = (i < 1024) ? bq[i] : (i < 2048 ? bk[i - 1024] : bv[i - 2048]);
  o[i] = v;
}

// row softmax over scaled bf16 scores (row stride ld); mask applied here.
// FUSED=1: also writes the fp32 attention row in place (Sb row r lives in the
// upper half of fp32 row r's slot; each block clobbers only its own input;
// the reduction __syncthreads orders all loads before any fp32 store).
template <int FUSED>
__global__ __launch_bounds__(256) void softmax_rows(const short* __restrict__ Sb,
                                                    const int* __restrict__ mask,
                                                    short* __restrict__ Pb,
                                                    float* __restrict__ Af,
                                                    int ld) {
  const long row = blockIdx.x;
  const bf16x8* src = (const bf16x8*)(Sb + row * ld);
  const int* mrow = mask + row * (long)SEQ;
  bf16x8* dst = (bf16x8*)(Pb + row * SEQ);
  const int tid = threadIdx.x;
  const int wid = tid >> 6, lane = tid & 63;
  bf16x8 a = src[tid], b = src[tid + 256];
  int4 ma0 = *(const int4*)(mrow + tid * 8);
  int4 ma1 = *(const int4*)(mrow + tid * 8 + 4);
  int4 mb0 = *(const int4*)(mrow + 2048 + tid * 8);
  int4 mb1 = *(const int4*)(mrow + 2048 + tid * 8 + 4);
  float v[16];
#pragma unroll
  for (int j = 0; j < 8; j++) { v[j] = bf2f(a[j]); v[8 + j] = bf2f(b[j]); }
  const int* mm0 = (const int*)&ma0;
  const int* mm1 = (const int*)&ma1;
  const int* mm2 = (const int*)&mb0;
  const int* mm3 = (const int*)&mb1;
#pragma unroll
  for (int j = 0; j < 4; j++) {
    if (mm0[j]) v[j] = -INFINITY;
    if (mm1[j]) v[4 + j] = -INFINITY;
    if (mm2[j]) v[8 + j] = -INFINITY;
    if (mm3[j]) v[12 + j] = -INFINITY;
  }
  float mx = -INFINITY;
#pragma unroll
  for (int j = 0; j < 16; j++) mx = fmaxf(mx, v[j]);
  mx = wave_max(mx);
  __shared__ float red[4];
  if (lane == 0) red[wid] = mx;
  __syncthreads();
  mx = fmaxf(fmaxf(red[0], red[1]), fmaxf(red[2], red[3]));
  float sum = 0.f;
#pragma unroll
  for (int j = 0; j < 16; j++) {
    v[j] = __expf(v[j] - mx);
    sum += v[j];
  }
  sum = wave_sum(sum);
  __shared__ float red2[4];
  if (lane == 0) red2[wid] = sum;
  __syncthreads();
  sum = red2[0] + red2[1] + red2[2] + red2[3];
  const float inv = 1.0f / sum;
  bf16x8 o0, o1;
#pragma unroll
  for (int j = 0; j < 8; j++) {
    v[j] *= inv;
    v[8 + j] *= inv;
    o0[j] = f2bf(v[j]);
    o1[j] = f2bf(v[8 + j]);
  }
  dst[tid] = o0;
  dst[tid + 256] = o1;
  if (FUSED) {
    float* orow = Af + row * (long)SEQ;
    *(float4*)(orow + tid * 8) = (float4){v[0], v[1], v[2], v[3]};
    *(float4*)(orow + tid * 8 + 4) = (float4){v[4], v[5], v[6], v[7]};
    *(float4*)(orow + 2048 + tid * 8) = (float4){v[8], v[9], v[10], v[11]};
    *(float4*)(orow + 2048 + tid * 8 + 4) = (float4){v[12], v[13], v[14], v[15]};
  }
}

// attention fp32 output = expand of bf16 probs (non-fused path only)
__global__ __launch_bounds__(256) void expand_bf16_f32(
    const short* __restrict__ in, float* __restrict__ out) {
  long i = (long)blockIdx.x * 256 + threadIdx.x;
  bf16x8 a = ((const bf16x8*)in)[i];
  float4 lo, hi;
  lo.x = bf2f(a[0]); lo.y = bf2f(a[1]); lo.z = bf2f(a[2]); lo.w = bf2f(a[3]);
  hi.x = bf2f(a[4]); hi.y = bf2f(a[5]); hi.z = bf2f(a[6]); hi.w = bf2f(a[7]);
  ((float4*)out)[2 * i] = lo;
  ((float4*)out)[2 * i + 1] = hi;
}

// context = sum of 4 AV partials + x -> bf16
__global__ __launch_bounds__(256) void reduce_ctx4(
    const short* __restrict__ p, const float* __restrict__ x,
    short* __restrict__ cb) {
  const long i = (long)blockIdx.x * 256 + threadIdx.x;
  bf16x8 a = ((const bf16x8*)p)[i];
  bf16x8 b = ((const bf16x8*)(p + 4194304))[i];
  bf16x8 c = ((const bf16x8*)(p + 8388608))[i];
  bf16x8 d = ((const bf16x8*)(p + 12582912))[i];
  float4 x0 = ((const float4*)x)[2 * i];
  float4 x1 = ((const float4*)x)[2 * i + 1];
  float xs[8] = {x0.x, x0.y, x0.z, x0.w, x1.x, x1.y, x1.z, x1.w};
  bf16x8 o;
#pragma unroll
  for (int j = 0; j < 8; j++)
    o[j] = f2bf(bf2f(a[j]) + bf2f(b[j]) + bf2f(c[j]) + bf2f(d[j]) + xs[j]);
  ((bf16x8*)cb)[i] = o;
}

// LayerNorm fused with the 4-way out-proj split reduce + bias.
__global__ __launch_bounds__(256) void ln4(
    const short* __restrict__ ph, const float* __restrict__ bo,
    const float* __restrict__ gamma, const float* __restrict__ beta,
    float* __restrict__ out) {
  const long row = blockIdx.x;
  const int tid = threadIdx.x;
  const int wid = tid >> 6, lane = tid & 63;
  const long base = row * DM + tid * 4;
  short4 p0 = *(const short4*)(ph + base);
  short4 p1 = *(const short4*)(ph + 4194304 + base);
  short4 p2 = *(const short4*)(ph + 8388608 + base);
  short4 p3 = *(const short4*)(ph + 12582912 + base);
  float4 bb = *(const float4*)(bo + tid * 4);
  float v[4];
  v[0] = bf2f(p0.x) + bf2f(p1.x) + bf2f(p2.x) + bf2f(p3.x) + bb.x;
  v[1] = bf2f(p0.y) + bf2f(p1.y) + bf2f(p2.y) + bf2f(p3.y) + bb.y;
  v[2] = bf2f(p0.z) + bf2f(p1.z) + bf2f(p2.z) + bf2f(p3.z) + bb.z;
  v[3] = bf2f(p0.w) + bf2f(p1.w) + bf2f(p2.w) + bf2f(p3.w) + bb.w;
  float s = v[0] + v[1] + v[2] + v[3];
  s = wave_sum(s);
  __shared__ float red[4];
  if (lane == 0) red[wid] = s;
  __syncthreads();
  const float mu = (red[0] + red[1] + red[2] + red[3]) * (1.f / DM);
  float var = 0.f;
#pragma unroll
  for (int j = 0; j < 4; j++) {
    float d = v[j] - mu;
    var += d * d;
  }
  var = wave_sum(var);
  __shared__ float red2[4];
  if (lane == 0) red2[wid] = var;
  __syncthreads();
  var = (red2[0] + red2[1] + red2[2] + red2[3]) * (1.f / DM);
  const float inv = rsqrtf(var + 1e-5f);
  float4 g = *(const float4*)(gamma + tid * 4);
  float4 be = *(const float4*)(beta + tid * 4);
  float4 o;
  o.x = (v[0] - mu) * inv * g.x + be.x;
  o.y = (v[1] - mu) * inv * g.y + be.y;
  o.z = (v[2] - mu) * inv * g.z + be.z;
  o.w = (v[3] - mu) * inv * g.w + be.w;
  *(float4*)(out + base) = o;
}

extern "C" void kernel_launch(void* const* d_in, const int* in_sizes, int n_in,
                              void* d_out, int out_size, void* d_ws,
                              size_t ws_size, hipStream_t stream) {
  const float* x    = (const float*)d_in[0];
  const int* mask   = (const int*)d_in[1];
  const float* wq   = (const float*)d_in[2];
  const float* bq   = (const float*)d_in[3];
  const float* wk   = (const float*)d_in[4];
  const float* bk   = (const float*)d_in[5];
  const float* wv   = (const float*)d_in[6];
  const float* bv   = (const float*)d_in[7];
  const float* wo   = (const float*)d_in[8];
  const float* bo   = (const float*)d_in[9];
  const float* gamma = (const float*)d_in[10];
  const float* beta  = (const float*)d_in[11];

  float* out  = (float*)d_out;             // final output [4096*1024] fp32
  float* attn = out + 4194304;             // attention [4096*4096] fp32
  short* cbuf = (short*)out;               // context bf16 (8 MiB, dead before LN)

  char* w = (char*)d_ws;
  // fused path (needs ws >= 80 MiB + bias): Sb interleaved in attn slots
  // (softmax writes fp32 in place, expand dies); pav/ph in ws[48,80).
  const bool fused = ws_size >= (size_t)83886080 + 16384;
  short* Sb   = fused ? (short*)attn + 4096 : (short*)attn;
  const int ldS = fused ? 8192 : 4096;
  short* pav  = fused ? (short*)(w + 50331648) : (short*)attn;
  short* phh  = fused ? pav : (short*)(attn + 8388608);
  float* bqkv = fused ? (float*)(w + 83886080) : (float*)(w + 50331648);

  // ws (MiB): wqkvT[0,6) woT[6,8) xb[8,16) qkv[16,40) vT[40,48)
  //           attnb[8,40) aliases xb+qkv once both are dead
  short* wqkvT = (short*)(w + 0);
  short* woT   = (short*)(w + 6291456);
  short* xb    = (short*)(w + 8388608);
  short* qkv   = (short*)(w + 16777216);
  short* attnb = (short*)(w + 8388608);
  short* vT    = (short*)(w + 41943040);

  // ---- prep ----
  cvt_f32_to_bf16<<<4096, 256, 0, stream>>>(x, xb, 1048576);
  transpose_w4<<<dim3(32, 32, 4), dim3(32, 8), 0, stream>>>(
      wq, wk, wv, wo, wqkvT, wqkvT + 1048576, wqkvT + 2097152, woT);
  concat_bias<<<12, 256, 0, stream>>>(bq, bk, bv, bqkv);

  // ---- qkv = x @ [wq|wk|wv] + b, v-part written transposed to vT ----
  gemm8<3><<<192, 512, 0, stream>>>(xb, wqkvT, qkv, vT, bqkv,
                                    1024, 1024, 1024, 3072, 4096, 1.f,
                                    16, 12, 0, 6);

  // ---- scores: bf16 (q k^T)/8 -> Sb (mask applied in softmax) ----
  gemm8<2><<<256, 512, 0, stream>>>(qkv, qkv + 1024, Sb, nullptr, nullptr,
                                    1024, 3072, 3072, ldS, 0, 0.125f,
                                    16, 16, 0, 8);

  // ---- softmax (+mask) -> bf16 probs (+ fp32 attention if fused) ----
  if (fused)
    softmax_rows<1><<<SEQ, 256, 0, stream>>>(Sb, mask, attnb, attn, ldS);
  else
    softmax_rows<0><<<SEQ, 256, 0, stream>>>(Sb, mask, attnb, attn, ldS);

  // ---- AV split-K=4 -> 4 bf16 partials ----
  gemm8<0><<<256, 512, 0, stream>>>(attnb, vT, pav, nullptr, nullptr,
                                    1024, 4096, 4096, 1024, 0, 1.f,
                                    16, 4, 4194304L, 4);

  // context = sum partials + x -> bf16
  reduce_ctx4<<<2048, 256, 0, stream>>>(pav, x, cbuf);

  // ---- out-proj split-K=4 -> 4 bf16 partials (reuses pav region if fused) --
  gemm8<0><<<256, 512, 0, stream>>>(cbuf, woT, phh, nullptr, nullptr,
                                    256, 1024, 1024, 1024, 0, 1.f,
                                    16, 4, 4194304L, 4);

  // ---- LayerNorm fused with partial-reduce + bias ----
  ln4<<<SEQ, 256, 0, stream>>>(phh, bo, gamma, beta, out);

  // ---- attention fp32 output (non-fused path only) ----
  if (!fused) expand_bf16_f32<<<8192, 256, 0, stream>>>(attnb, attn);
}

// Round 12
// 188.995 us; speedup vs baseline: 1.0419x; 1.0419x over previous
//
#include <hip/hip_runtime.h>
#include <hip/hip_bf16.h>
#include <stdint.h>

#define SEQ 4096
#define DM  1024

typedef __attribute__((ext_vector_type(8))) short bf16x8;
typedef __attribute__((ext_vector_type(4))) float f32x4;

template <int V> struct Int { static constexpr int v = V; };

__device__ __forceinline__ short f2bf(float f) {
  union { float f; unsigned int i; } x; x.f = f;
  unsigned int r = x.i + 0x7FFFu + ((x.i >> 16) & 1u);
  return (short)(r >> 16);
}
__device__ __forceinline__ float bf2f(short s) {
  union { unsigned int i; float f; } u;
  u.i = ((unsigned int)(unsigned short)s) << 16;
  return u.f;
}

__device__ __forceinline__ void gload16(const short* g, short* l) {
  __builtin_amdgcn_global_load_lds(
      (const __attribute__((address_space(1))) unsigned int*)g,
      (__attribute__((address_space(3))) unsigned int*)l, 16, 0, 0);
}

__device__ __forceinline__ float wave_max(float v) {
#pragma unroll
  for (int o = 32; o; o >>= 1) v = fmaxf(v, __shfl_xor(v, o));
  return v;
}
__device__ __forceinline__ float wave_sum(float v) {
#pragma unroll
  for (int o = 32; o; o >>= 1) v += __shfl_xor(v, o);
  return v;
}

#define BARRIER() do { asm volatile("" ::: "memory"); \
  __builtin_amdgcn_s_barrier(); asm volatile("" ::: "memory"); } while (0)
#define MF(a, b, c) __builtin_amdgcn_mfma_f32_16x16x32_bf16(a, b, c, 0, 0, 0)

// ---------------------------------------------------------------------------
// 256x256-tile bf16 GEMM, 16x16x32 MFMA, k-slice-LEVELED 8-phase schedule.
// Round-10 base (2-buf A + 2-buf B, 128 KiB LDS, minimal barriers, vmcnt(4)
// 12-outstanding ledger) with each 16-MFMA phase split into two 8-MFMA
// k-slice phases. LDS read bursts per tile: (6,6,2,2,2,2,2,2) instead of
// (12,4,4,4) -- halves the post-barrier in-phase ds_read burst so the two
// waves per SIMD can anti-phase (one reads while the other MFMAs; setprio
// arbitrates). Total reads/MFMA per tile unchanged (24 reads, 64 MFMA/wave).
// Barriers: 2 per tile -- end of P2 (all waves' B-frag reads of this buf
// done -> P3/P4 stB overwrite safe; ldsA/ldsB disjoint so A reads through
// P8 unaffected) and the boundary vmcnt+barrier.
// Ledger (identical to round 10): at each boundary 12 outstanding
// [prevB(t+1)4, A(t+1)4, B(t+2)4]; vmcnt(4) drains exactly tile t+1's 8.
// Tails vmcnt(0). LDS swizzle: byte ^= ((byte>>7)&7)<<4 (0 conflicts,
// verified); involution pre-applied to the gload source.
// EPI: 0 plain bf16; 1 +bias; 2 *scale; 3 QKV (bias, v-cols -> transposed Cv).
// ---------------------------------------------------------------------------
template <int EPI>
__global__ __launch_bounds__(512, 2) void gemm8(
    const short* __restrict__ A, const short* __restrict__ B,
    short* __restrict__ C, short* __restrict__ Cv,
    const float* __restrict__ bias, int Ksplit, int lda, int ldb, int ldc,
    int ldv, float scale, int ntm, int ntn, long csplit, int pc) {
  __shared__ short lds[2][4][8192];  // [buf][A0,A1,B0,B1][128 rows x 64 k]
  const int tid = threadIdx.x;
  const int lane = tid & 63;
  const int wid = tid >> 6;   // 0..7
  const int wr = wid >> 2;    // 0,1  -> A half / output row half
  const int wc = wid & 3;     // 0..3 -> 64-col group
  const int bid = blockIdx.x, nwg = gridDim.x;
  const int chunk = nwg >> 3;
  const int wl = (bid & 7) * chunk + (bid >> 3);  // contiguous per XCD
  const int tpg = ntm * ntn;
  const int split = wl / tpg;
  const int r0 = wl - split * tpg;
  const int q = r0 / chunk, i0 = r0 % chunk;
  const int npatch = ntn / pc;
  const int m0 = ((q / npatch) * (chunk / pc) + i0 / pc) * 256;
  const int n0 = ((q % npatch) * pc + i0 % pc) * 256;
  const short* Ab = A + (long)split * Ksplit;
  const short* Bb = B + (long)split * Ksplit;
  short* Co = C + (long)split * csplit;

  // staging: thread t fills half-tile bytes [t*16, t*16+16) linearly; source
  // address pre-swizzled with the involution swz(b) = b ^ (((b>>7)&7)<<4).
  const int o0 = tid * 16;
  const int oo = o0 ^ (((o0 >> 7) & 7) << 4);
  const int sr0 = oo >> 7;           // source row 0..63
  const int sc0 = (oo & 127) >> 1;   // source col in shorts (8-mult)

  auto stA = [&](int buf, int h, int kt) {
    const short* g = Ab + (long)(m0 + h * 128 + sr0) * lda + kt * 64 + sc0;
    short* l = &lds[buf][h][0] + wid * 512;
    gload16(g, l);
    gload16(g + (long)64 * lda, l + 4096);
  };
  auto stB = [&](int buf, int h, int kt) {
    const short* g = Bb + (long)(n0 + h * 128 + sr0) * ldb + kt * 64 + sc0;
    short* l = &lds[buf][2 + h][0] + wid * 512;
    gload16(g, l);
    gload16(g + (long)64 * ldb, l + 4096);
  };

  const int ll = lane & 15, lh = lane >> 4;
  // fragment reads: short-offset XOR (r&7)<<3 == byte XOR (r&7)<<4
  auto ldaf = [&](int buf, int c, int mm, int kk) {
    const int r = c * 32 + mm * 16 + ll;
    const int off = (r * 64 + kk * 32 + lh * 8) ^ ((r & 7) << 3);
    return *(const bf16x8*)(&lds[buf][wr][0] + off);
  };
  auto ldbf = [&](int buf, int n, int kk) {
    const int r = (wc & 1) * 64 + n * 16 + ll;
    const int off = (r * 64 + kk * 32 + lh * 8) ^ ((r & 7) << 3);
    return *(const bf16x8*)(&lds[buf][2 + (wc >> 1)][0] + off);
  };

  f32x4 acc[8][4];
#pragma unroll
  for (int i = 0; i < 8; i++)
#pragma unroll
    for (int j = 0; j < 4; j++) acc[i][j] = (f32x4){0.f, 0.f, 0.f, 0.f};
  bf16x8 Bf[4][2];

  const int NT = Ksplit >> 6;  // even, >= 4 at all call sites
  // prologue: B(0,*,0), A(0,*,0), B(1,*,1) = 12 loads; vmcnt(4) drains buf0.
  stB(0, 0, 0); stB(0, 1, 0);
  stA(0, 0, 0); stA(0, 1, 0);
  stB(1, 0, 1); stB(1, 1, 1);
  asm volatile("s_waitcnt vmcnt(4)" ::: "memory");
  BARRIER();

  // k-slice phase: [B-frags for slice kk?] [2 A-frags] [stage] [barrier?]
  //                [8 MFMA: band c, slice kk]
  auto phase = [&](auto BUF, auto CC, auto KK, auto LBF, auto BARv,
                   auto&& stg) {
    constexpr int buf = decltype(BUF)::v;
    constexpr int c = decltype(CC)::v;
    constexpr int kk = decltype(KK)::v;
    if constexpr (decltype(LBF)::v != 0) {
#pragma unroll
      for (int n = 0; n < 4; n++) Bf[n][kk] = ldbf(buf, n, kk);
    }
    bf16x8 a0 = ldaf(buf, c, 0, kk);
    bf16x8 a1 = ldaf(buf, c, 1, kk);
    stg();
    if constexpr (decltype(BARv)::v != 0) BARRIER();
    __builtin_amdgcn_s_setprio(1);
#pragma unroll
    for (int n = 0; n < 4; n++) {
      acc[2 * c][n] = MF(a0, Bf[n][kk], acc[2 * c][n]);
      acc[2 * c + 1][n] = MF(a1, Bf[n][kk], acc[2 * c + 1][n]);
    }
    __builtin_amdgcn_s_setprio(0);
  };

  for (int t = 0; t < NT; t += 2) {
    const bool nl = (t + 2 < NT);
    // group A: tile t (buf0)
    phase(Int<0>{}, Int<0>{}, Int<0>{}, Int<1>{}, Int<0>{},
          [&] { stA(1, 0, t + 1); });
    phase(Int<0>{}, Int<0>{}, Int<1>{}, Int<1>{}, Int<1>{},
          [&] { stA(1, 1, t + 1); });           // barrier: B-frag reads done
    phase(Int<0>{}, Int<1>{}, Int<0>{}, Int<0>{}, Int<0>{},
          [&] { if (nl) stB(0, 0, t + 2); });
    phase(Int<0>{}, Int<1>{}, Int<1>{}, Int<0>{}, Int<0>{},
          [&] { if (nl) stB(0, 1, t + 2); });
    phase(Int<0>{}, Int<2>{}, Int<0>{}, Int<0>{}, Int<0>{}, [] {});
    phase(Int<0>{}, Int<2>{}, Int<1>{}, Int<0>{}, Int<0>{}, [] {});
    phase(Int<0>{}, Int<3>{}, Int<0>{}, Int<0>{}, Int<0>{}, [] {});
    phase(Int<0>{}, Int<3>{}, Int<1>{}, Int<0>{}, Int<0>{}, [] {});
    // boundary into buf1
    if (nl) { asm volatile("s_waitcnt vmcnt(4)" ::: "memory"); }
    else    { asm volatile("s_waitcnt vmcnt(0)" ::: "memory"); }
    BARRIER();
    // group B: tile t+1 (buf1)
    phase(Int<1>{}, Int<0>{}, Int<0>{}, Int<1>{}, Int<0>{},
          [&] { if (nl) stA(0, 0, t + 2); });
    phase(Int<1>{}, Int<0>{}, Int<1>{}, Int<1>{}, Int<1>{},
          [&] { if (nl) stA(0, 1, t + 2); });   // barrier
    phase(Int<1>{}, Int<1>{}, Int<0>{}, Int<0>{}, Int<0>{},
          [&] { if (nl) stB(1, 0, t + 3); });
    phase(Int<1>{}, Int<1>{}, Int<1>{}, Int<0>{}, Int<0>{},
          [&] { if (nl) stB(1, 1, t + 3); });
    phase(Int<1>{}, Int<2>{}, Int<0>{}, Int<0>{}, Int<0>{}, [] {});
    phase(Int<1>{}, Int<2>{}, Int<1>{}, Int<0>{}, Int<0>{}, [] {});
    phase(Int<1>{}, Int<3>{}, Int<0>{}, Int<0>{}, Int<0>{}, [] {});
    phase(Int<1>{}, Int<3>{}, Int<1>{}, Int<0>{}, Int<0>{}, [] {});
    // boundary into buf0 of next iteration (skip after the last tile)
    if (nl) {
      asm volatile("s_waitcnt vmcnt(4)" ::: "memory");
      BARRIER();
    }
  }

  // epilogue: wave writes 128x64 at (m0 + wr*128, n0 + wc*64)
  const int rb = m0 + wr * 128 + lh * 4;
  const int cb0 = n0 + wc * 64 + ll;
  if (EPI == 3 && n0 >= 2048) {
    // v-block: bias + packed transposed write to vT[col-2048][row]
#pragma unroll
    for (int mi = 0; mi < 8; mi++) {
#pragma unroll
      for (int n = 0; n < 4; n++) {
        const int col = cb0 + n * 16;
        const float bv = bias[col];
        short4 pk;
        pk.x = f2bf(acc[mi][n][0] + bv);
        pk.y = f2bf(acc[mi][n][1] + bv);
        pk.z = f2bf(acc[mi][n][2] + bv);
        pk.w = f2bf(acc[mi][n][3] + bv);
        *(short4*)(Cv + (long)(col - 2048) * ldv + rb + mi * 16) = pk;
      }
    }
    return;
  }
#pragma unroll
  for (int mi = 0; mi < 8; mi++) {
#pragma unroll
    for (int n = 0; n < 4; n++) {
      const int col = cb0 + n * 16;
      float bv = 0.f;
      if (EPI == 1 || EPI == 3) bv = bias[col];
#pragma unroll
      for (int r = 0; r < 4; r++) {
        const int row = rb + mi * 16 + r;
        const long off = (long)row * ldc + col;
        float v = acc[mi][n][r];
        if (EPI == 1 || EPI == 3) v += bv;
        if (EPI == 2) v *= scale;
        Co[off] = f2bf(v);
      }
    }
  }
}

// ---------------------------------------------------------------------------

// One launch for all prep: z=0..3 transpose the four 1024x1024 weights
// (fp32 -> bf16, [K,N] -> [N,K]); z=4 blocks convert x to bf16 and the first
// 3072 threads also build bqkv = [bq|bk|bv].
__global__ void prep_all(const float* __restrict__ x, short* __restrict__ xb,
                         const float* __restrict__ s0,
                         const float* __restrict__ s1,
                         const float* __restrict__ s2,
                         const float* __restrict__ s3,
                         short* __restrict__ d0, short* __restrict__ d1,
                         short* __restrict__ d2, short* __restrict__ d3,
                         const float* __restrict__ bq,
                         const float* __restrict__ bk,
                         const float* __restrict__ bv,
                         float* __restrict__ bqkv) {
  const int z = blockIdx.z;
  const int tx = threadIdx.x, ty = threadIdx.y;
  if (z == 4) {
    const int flat = (blockIdx.y * 32 + blockIdx.x) * 256 + ty * 32 + tx;
    const float4* xs = (const float4*)x;
    short4* xd = (short4*)xb;
#pragma unroll
    for (int j = 0; j < 4; j++) {
      float4 f = xs[j * 262144 + flat];
      short4 o;
      o.x = f2bf(f.x); o.y = f2bf(f.y); o.z = f2bf(f.z); o.w = f2bf(f.w);
      xd[j * 262144 + flat] = o;
    }
    if (flat < 3072) {
      float v = (flat < 1024) ? bq[flat]
                              : (flat < 2048 ? bk[flat - 1024] : bv[flat - 2048]);
      bqkv[flat] = v;
    }
    return;
  }
  const float* in = z == 0 ? s0 : z == 1 ? s1 : z == 2 ? s2 : s3;
  short* out = z == 0 ? d0 : z == 1 ? d1 : z == 2 ? d2 : d3;
  __shared__ float tile[32][33];
  const int bx = blockIdx.x * 32;
  const int by = blockIdx.y * 32;
#pragma unroll
  for (int i = 0; i < 32; i += 8)
    tile[ty + i][tx] = in[(long)(by + ty + i) * 1024 + bx + tx];
  __syncthreads();
#pragma unroll
  for (int i = 0; i < 32; i += 8)
    out[(long)(bx + ty + i) * 1024 + by + tx] = f2bf(tile[tx][ty + i]);
}

// row softmax over scaled bf16 scores (row stride ld); mask applied here.
// FUSED=1: also writes the fp32 attention row in place (Sb row r lives in the
// upper half of fp32 row r's slot; each block clobbers only its own input;
// the reduction __syncthreads orders all loads before any fp32 store).
template <int FUSED>
__global__ __launch_bounds__(256) void softmax_rows(const short* __restrict__ Sb,
                                                    const int* __restrict__ mask,
                                                    short* __restrict__ Pb,
                                                    float* __restrict__ Af,
                                                    int ld) {
  const long row = blockIdx.x;
  const bf16x8* src = (const bf16x8*)(Sb + row * ld);
  const int* mrow = mask + row * (long)SEQ;
  bf16x8* dst = (bf16x8*)(Pb + row * SEQ);
  const int tid = threadIdx.x;
  const int wid = tid >> 6, lane = tid & 63;
  bf16x8 a = src[tid], b = src[tid + 256];
  int4 ma0 = *(const int4*)(mrow + tid * 8);
  int4 ma1 = *(const int4*)(mrow + tid * 8 + 4);
  int4 mb0 = *(const int4*)(mrow + 2048 + tid * 8);
  int4 mb1 = *(const int4*)(mrow + 2048 + tid * 8 + 4);
  float v[16];
#pragma unroll
  for (int j = 0; j < 8; j++) { v[j] = bf2f(a[j]); v[8 + j] = bf2f(b[j]); }
  const int* mm0 = (const int*)&ma0;
  const int* mm1 = (const int*)&ma1;
  const int* mm2 = (const int*)&mb0;
  const int* mm3 = (const int*)&mb1;
#pragma unroll
  for (int j = 0; j < 4; j++) {
    if (mm0[j]) v[j] = -INFINITY;
    if (mm1[j]) v[4 + j] = -INFINITY;
    if (mm2[j]) v[8 + j] = -INFINITY;
    if (mm3[j]) v[12 + j] = -INFINITY;
  }
  float mx = -INFINITY;
#pragma unroll
  for (int j = 0; j < 16; j++) mx = fmaxf(mx, v[j]);
  mx = wave_max(mx);
  __shared__ float red[4];
  if (lane == 0) red[wid] = mx;
  __syncthreads();
  mx = fmaxf(fmaxf(red[0], red[1]), fmaxf(red[2], red[3]));
  float sum = 0.f;
#pragma unroll
  for (int j = 0; j < 16; j++) {
    v[j] = __expf(v[j] - mx);
    sum += v[j];
  }
  sum = wave_sum(sum);
  __shared__ float red2[4];
  if (lane == 0) red2[wid] = sum;
  __syncthreads();
  sum = red2[0] + red2[1] + red2[2] + red2[3];
  const float inv = 1.0f / sum;
  bf16x8 o0, o1;
#pragma unroll
  for (int j = 0; j < 8; j++) {
    v[j] *= inv;
    v[8 + j] *= inv;
    o0[j] = f2bf(v[j]);
    o1[j] = f2bf(v[8 + j]);
  }
  dst[tid] = o0;
  dst[tid + 256] = o1;
  if (FUSED) {
    float* orow = Af + row * (long)SEQ;
    *(float4*)(orow + tid * 8) = (float4){v[0], v[1], v[2], v[3]};
    *(float4*)(orow + tid * 8 + 4) = (float4){v[4], v[5], v[6], v[7]};
    *(float4*)(orow + 2048 + tid * 8) = (float4){v[8], v[9], v[10], v[11]};
    *(float4*)(orow + 2048 + tid * 8 + 4) = (float4){v[12], v[13], v[14], v[15]};
  }
}

// attention fp32 output = expand of bf16 probs (non-fused path only)
__global__ __launch_bounds__(256) void expand_bf16_f32(
    const short* __restrict__ in, float* __restrict__ out) {
  long i = (long)blockIdx.x * 256 + threadIdx.x;
  bf16x8 a = ((const bf16x8*)in)[i];
  float4 lo, hi;
  lo.x = bf2f(a[0]); lo.y = bf2f(a[1]); lo.z = bf2f(a[2]); lo.w = bf2f(a[3]);
  hi.x = bf2f(a[4]); hi.y = bf2f(a[5]); hi.z = bf2f(a[6]); hi.w = bf2f(a[7]);
  ((float4*)out)[2 * i] = lo;
  ((float4*)out)[2 * i + 1] = hi;
}

// context = sum of 4 AV partials + x -> bf16
__global__ __launch_bounds__(256) void reduce_ctx4(
    const short* __restrict__ p, const float* __restrict__ x,
    short* __restrict__ cb) {
  const long i = (long)blockIdx.x * 256 + threadIdx.x;
  bf16x8 a = ((const bf16x8*)p)[i];
  bf16x8 b = ((const bf16x8*)(p + 4194304))[i];
  bf16x8 c = ((const bf16x8*)(p + 8388608))[i];
  bf16x8 d = ((const bf16x8*)(p + 12582912))[i];
  float4 x0 = ((const float4*)x)[2 * i];
  float4 x1 = ((const float4*)x)[2 * i + 1];
  float xs[8] = {x0.x, x0.y, x0.z, x0.w, x1.x, x1.y, x1.z, x1.w};
  bf16x8 o;
#pragma unroll
  for (int j = 0; j < 8; j++)
    o[j] = f2bf(bf2f(a[j]) + bf2f(b[j]) + bf2f(c[j]) + bf2f(d[j]) + xs[j]);
  ((bf16x8*)cb)[i] = o;
}

// LayerNorm fused with the 4-way out-proj split reduce + bias.
__global__ __launch_bounds__(256) void ln4(
    const short* __restrict__ ph, const float* __restrict__ bo,
    const float* __restrict__ gamma, const float* __restrict__ beta,
    float* __restrict__ out) {
  const long row = blockIdx.x;
  const int tid = threadIdx.x;
  const int wid = tid >> 6, lane = tid & 63;
  const long base = row * DM + tid * 4;
  short4 p0 = *(const short4*)(ph + base);
  short4 p1 = *(const short4*)(ph + 4194304 + base);
  short4 p2 = *(const short4*)(ph + 8388608 + base);
  short4 p3 = *(const short4*)(ph + 12582912 + base);
  float4 bb = *(const float4*)(bo + tid * 4);
  float v[4];
  v[0] = bf2f(p0.x) + bf2f(p1.x) + bf2f(p2.x) + bf2f(p3.x) + bb.x;
  v[1] = bf2f(p0.y) + bf2f(p1.y) + bf2f(p2.y) + bf2f(p3.y) + bb.y;
  v[2] = bf2f(p0.z) + bf2f(p1.z) + bf2f(p2.z) + bf2f(p3.z) + bb.z;
  v[3] = bf2f(p0.w) + bf2f(p1.w) + bf2f(p2.w) + bf2f(p3.w) + bb.w;
  float s = v[0] + v[1] + v[2] + v[3];
  s = wave_sum(s);
  __shared__ float red[4];
  if (lane == 0) red[wid] = s;
  __syncthreads();
  const float mu = (red[0] + red[1] + red[2] + red[3]) * (1.f / DM);
  float var = 0.f;
#pragma unroll
  for (int j = 0; j < 4; j++) {
    float d = v[j] - mu;
    var += d * d;
  }
  var = wave_sum(var);
  __shared__ float red2[4];
  if (lane == 0) red2[wid] = var;
  __syncthreads();
  var = (red2[0] + red2[1] + red2[2] + red2[3]) * (1.f / DM);
  const float inv = rsqrtf(var + 1e-5f);
  float4 g = *(const float4*)(gamma + tid * 4);
  float4 be = *(const float4*)(beta + tid * 4);
  float4 o;
  o.x = (v[0] - mu) * inv * g.x + be.x;
  o.y = (v[1] - mu) * inv * g.y + be.y;
  o.z = (v[2] - mu) * inv * g.z + be.z;
  o.w = (v[3] - mu) * inv * g.w + be.w;
  *(float4*)(out + base) = o;
}

extern "C" void kernel_launch(void* const* d_in, const int* in_sizes, int n_in,
                              void* d_out, int out_size, void* d_ws,
                              size_t ws_size, hipStream_t stream) {
  const float* x    = (const float*)d_in[0];
  const int* mask   = (const int*)d_in[1];
  const float* wq   = (const float*)d_in[2];
  const float* bq   = (const float*)d_in[3];
  const float* wk   = (const float*)d_in[4];
  const float* bk   = (const float*)d_in[5];
  const float* wv   = (const float*)d_in[6];
  const float* bv   = (const float*)d_in[7];
  const float* wo   = (const float*)d_in[8];
  const float* bo   = (const float*)d_in[9];
  const float* gamma = (const float*)d_in[10];
  const float* beta  = (const float*)d_in[11];

  float* out  = (float*)d_out;             // final output [4096*1024] fp32
  float* attn = out + 4194304;             // attention [4096*4096] fp32
  short* cbuf = (short*)out;               // context bf16 (8 MiB, dead before LN)

  char* w = (char*)d_ws;
  // fused path (needs ws >= 80 MiB + bias): Sb interleaved in attn slots
  // (softmax writes fp32 in place, expand dies); pav/ph in ws[48,80).
  const bool fused = ws_size >= (size_t)83886080 + 16384;
  short* Sb   = fused ? (short*)attn + 4096 : (short*)attn;
  const int ldS = fused ? 8192 : 4096;
  short* pav  = fused ? (short*)(w + 50331648) : (short*)attn;
  short* phh  = fused ? pav : (short*)(attn + 8388608);
  float* bqkv = fused ? (float*)(w + 83886080) : (float*)(w + 50331648);

  // ws (MiB): wqkvT[0,6) woT[6,8) xb[8,16) qkv[16,40) vT[40,48)
  //           attnb[8,40) aliases xb+qkv once both are dead
  short* wqkvT = (short*)(w + 0);
  short* woT   = (short*)(w + 6291456);
  short* xb    = (short*)(w + 8388608);
  short* qkv   = (short*)(w + 16777216);
  short* attnb = (short*)(w + 8388608);
  short* vT    = (short*)(w + 41943040);

  // ---- prep: one launch (4 weight transposes + x cvt + bias concat) ----
  prep_all<<<dim3(32, 32, 5), dim3(32, 8), 0, stream>>>(
      x, xb, wq, wk, wv, wo, wqkvT, wqkvT + 1048576, wqkvT + 2097152, woT,
      bq, bk, bv, bqkv);

  // ---- qkv = x @ [wq|wk|wv] + b, v-part written transposed to vT ----
  gemm8<3><<<192, 512, 0, stream>>>(xb, wqkvT, qkv, vT, bqkv,
                                    1024, 1024, 1024, 3072, 4096, 1.f,
                                    16, 12, 0, 6);

  // ---- scores: bf16 (q k^T)/8 -> Sb (mask applied in softmax) ----
  gemm8<2><<<256, 512, 0, stream>>>(qkv, qkv + 1024, Sb, nullptr, nullptr,
                                    1024, 3072, 3072, ldS, 0, 0.125f,
                                    16, 16, 0, 8);

  // ---- softmax (+mask) -> bf16 probs (+ fp32 attention if fused) ----
  if (fused)
    softmax_rows<1><<<SEQ, 256, 0, stream>>>(Sb, mask, attnb, attn, ldS);
  else
    softmax_rows<0><<<SEQ, 256, 0, stream>>>(Sb, mask, attnb, attn, ldS);

  // ---- AV split-K=4 -> 4 bf16 partials ----
  gemm8<0><<<256, 512, 0, stream>>>(attnb, vT, pav, nullptr, nullptr,
                                    1024, 4096, 4096, 1024, 0, 1.f,
                                    16, 4, 4194304L, 4);

  // context = sum partials + x -> bf16
  reduce_ctx4<<<2048, 256, 0, stream>>>(pav, x, cbuf);

  // ---- out-proj split-K=4 -> 4 bf16 partials (reuses pav region if fused) --
  gemm8<0><<<256, 512, 0, stream>>>(cbuf, woT, phh, nullptr, nullptr,
                                    256, 1024, 1024, 1024, 0, 1.f,
                                    16, 4, 4194304L, 4);

  // ---- LayerNorm fused with partial-reduce + bias ----
  ln4<<<SEQ, 256, 0, stream>>>(phh, bo, gamma, beta, out);

  // ---- attention fp32 output (non-fused path only) ----
  if (!fused) expand_bf16_f32<<<8192, 256, 0, stream>>>(attnb, attn);
}